// Round 8
// baseline (682.311 us; speedup 1.0000x reference)
//
#include <hip/hip_runtime.h>
#include <hip/hip_bf16.h>
#include <hip/hip_fp16.h>

// Problem constants (B=8, T=4096, Din=Dout=256, WINDOW=2)
#define BDIM 8
#define TDIM 4096
#define DDIM 256
#define MDIM (BDIM * TDIM)      // 32768
#define NCHUNK 256              // chunks along T for the parallel scan
#define LCHUNK (TDIM / NCHUNK)  // 16

typedef _Float16 f16x8 __attribute__((ext_vector_type(8)));
typedef _Float16 f16x4 __attribute__((ext_vector_type(4)));
typedef float f32x4 __attribute__((ext_vector_type(4)));

__device__ __forceinline__ float sigmoid_(float x) {
    return 1.0f / (1.0f + __expf(-x));
}
__device__ __forceinline__ float tanh_(float x) {
    return 2.0f / (1.0f + __expf(-2.0f * x)) - 1.0f;
}

#define GLOAD_LDS16(g, l)                                                    \
    __builtin_amdgcn_global_load_lds(                                        \
        (const __attribute__((address_space(1))) void*)(g),                  \
        (__attribute__((address_space(3))) void*)(l), 16, 0, 0)

// ---------------------------------------------------------------------------
// Fused prep: blocks [0,1536) convert W, blocks [1536,9736) convert x.
// ---------------------------------------------------------------------------
__global__ __launch_bounds__(256) void prep(
    const float* __restrict__ x, _Float16* __restrict__ xpad,
    const float* __restrict__ Wz, const float* __restrict__ Wf,
    const float* __restrict__ Wo, _Float16* __restrict__ Wt) {
    const int bx = blockIdx.x;
    if (bx < 1536) {  // convert_w: 1536*256 = 3*2*256*256 threads
        const int idx = bx * 256 + threadIdx.x;
        const int n = idx & 255;
        const int kin = (idx >> 8) & 255;
        const int w = (idx >> 16) & 1;
        const int g = idx >> 17;
        const float* W = (g == 0) ? Wz : (g == 1) ? Wf : Wo;
        const float v = W[(size_t)w * 65536 + (size_t)kin * 256 + n];
        Wt[((size_t)g * 256 + n) * 512 + w * 256 + kin] = (_Float16)v;
        return;
    }
    const int bxx = bx - 1536;        // 8200 blocks: 1025 per batch
    const int b = bxx / 1025;
    const int tb = bxx - b * 1025;
    const int tp = tb * 4 + (threadIdx.x >> 6);  // padded row 0..4096
    const int q = threadIdx.x & 63;
    if (tp > TDIM) return;
    float4 v = make_float4(0.f, 0.f, 0.f, 0.f);
    if (tp > 0)
        v = *(const float4*)(x + ((size_t)b * TDIM + tp - 1) * DDIM + q * 4);
    f16x4 h;
    h[0] = (_Float16)v.x; h[1] = (_Float16)v.y;
    h[2] = (_Float16)v.z; h[3] = (_Float16)v.w;
    *(f16x4*)(xpad + ((size_t)b * (TDIM + 1) + tp) * DDIM + q * 4) = h;
}

// ---------------------------------------------------------------------------
// MFMA GEMM, BK=64 two-phase K-tiles (R7-verified, 42 us).  Unchanged.
// ---------------------------------------------------------------------------
__global__ __launch_bounds__(256, 2) void gates_mfma(
    const _Float16* __restrict__ xpad, const _Float16* __restrict__ Wt,
    const float* __restrict__ bz, const float* __restrict__ bfv,
    const float* __restrict__ bo,
    _Float16* __restrict__ zbuf, _Float16* __restrict__ fbuf,
    _Float16* __restrict__ obuf) {
    const int hw = blockIdx.x;
    const int logical = (hw & 7) * 192 + (hw >> 3);
    const int mblk = logical / 6;
    const int rem = logical - mblk * 6;   // (n,gate) innermost
    const int gate = rem % 3;
    const int nblk = rem / 3;
    const int m0 = mblk * 128;
    const int n0 = nblk * 128;

    const int tid = threadIdx.x;
    const int lane = tid & 63;
    const int wave = tid >> 6;
    const int wr = wave >> 1;
    const int wc = wave & 1;

    __shared__ __align__(16) char smem[65536];

    const int s = wave * 64 + lane;
    const int r1 = s >> 3;
    const int kc = (((s & 7) ^ ((s >> 3) & 7))) * 8;

    const int b = m0 >> 12;
    const int t0 = m0 & (TDIM - 1);

    const _Float16* srcA =
        xpad + ((size_t)b * (TDIM + 1) + t0 + r1) * DDIM + kc;
    const _Float16* srcB = Wt + ((size_t)gate * 256 + n0 + r1) * 512 + kc;

#define STAGE_(slot, kt)                                                     \
    {                                                                        \
        char* dA = smem + (slot) * 32768 + wave * 1024;                      \
        char* dB = smem + (slot) * 32768 + 16384 + wave * 1024;              \
        GLOAD_LDS16(srcA + (kt) * 64, dA);                                   \
        GLOAD_LDS16(srcA + (kt) * 64 + 32 * DDIM, dA + 4096);                \
        GLOAD_LDS16(srcA + (kt) * 64 + 64 * DDIM, dA + 8192);                \
        GLOAD_LDS16(srcA + (kt) * 64 + 96 * DDIM, dA + 12288);               \
        GLOAD_LDS16(srcB + (kt) * 64, dB);                                   \
        GLOAD_LDS16(srcB + (kt) * 64 + 32 * 512, dB + 4096);                 \
        GLOAD_LDS16(srcB + (kt) * 64 + 64 * 512, dB + 8192);                 \
        GLOAD_LDS16(srcB + (kt) * 64 + 96 * 512, dB + 12288);               \
    }

    f32x4 acc[4][4] = {};
    const int am = lane & 15;
    const int c0 = (((lane >> 4) ^ (lane & 7))) * 8;
    const int c1 = (((4 + (lane >> 4)) ^ (lane & 7))) * 8;

    STAGE_(0, 0);

#pragma unroll
    for (int t = 0; t < 8; ++t) {
        asm volatile("s_waitcnt vmcnt(0)" ::: "memory");
        __builtin_amdgcn_s_barrier();
        __builtin_amdgcn_sched_barrier(0);
        if (t < 7) STAGE_((t + 1) & 1, t + 1);

        const _Float16* Ab = (const _Float16*)(smem + (t & 1) * 32768);
        const _Float16* Bb = Ab + 8192;  // halves

        f16x8 a0[4], b0[4], a1[4], b1[4];
#pragma unroll
        for (int i = 0; i < 4; ++i)
            a0[i] = *(const f16x8*)(Ab + (wr * 64 + i * 16 + am) * 64 + c0);
#pragma unroll
        for (int j = 0; j < 4; ++j)
            b0[j] = *(const f16x8*)(Bb + (wc * 64 + j * 16 + am) * 64 + c0);
        __builtin_amdgcn_sched_barrier(0);
#pragma unroll
        for (int i = 0; i < 4; ++i)
            a1[i] = *(const f16x8*)(Ab + (wr * 64 + i * 16 + am) * 64 + c1);
#pragma unroll
        for (int j = 0; j < 4; ++j)
            b1[j] = *(const f16x8*)(Bb + (wc * 64 + j * 16 + am) * 64 + c1);

        asm volatile("s_waitcnt lgkmcnt(8)" ::: "memory");
        __builtin_amdgcn_sched_barrier(0);
        __builtin_amdgcn_s_setprio(1);
#pragma unroll
        for (int i = 0; i < 4; ++i)
#pragma unroll
            for (int j = 0; j < 4; ++j)
                acc[i][j] = __builtin_amdgcn_mfma_f32_16x16x32_f16(
                    b0[j], a0[i], acc[i][j], 0, 0, 0);
        __builtin_amdgcn_s_setprio(0);
        asm volatile("s_waitcnt lgkmcnt(0)" ::: "memory");
        __builtin_amdgcn_sched_barrier(0);
        __builtin_amdgcn_s_setprio(1);
#pragma unroll
        for (int i = 0; i < 4; ++i)
#pragma unroll
            for (int j = 0; j < 4; ++j)
                acc[i][j] = __builtin_amdgcn_mfma_f32_16x16x32_f16(
                    b1[j], a1[i], acc[i][j], 0, 0, 0);
        __builtin_amdgcn_s_setprio(0);
    }
#undef STAGE_

    const float* bias = (gate == 0) ? bz : (gate == 1) ? bfv : bo;
    _Float16* outp = (gate == 0) ? zbuf : (gate == 1) ? fbuf : obuf;
    const int nq = (lane >> 4) * 4;
#pragma unroll
    for (int i = 0; i < 4; ++i) {
        const size_t gm = (size_t)(m0 + wr * 64 + i * 16 + am);
#pragma unroll
        for (int j = 0; j < 4; ++j) {
            const int gc = n0 + wc * 64 + j * 16 + nq;
            const float4 b4 = *(const float4*)(bias + gc);
            f32x4 v = acc[i][j];
            f16x4 h;
            if (gate == 0) {
                h[0] = (_Float16)tanh_(v[0] + b4.x);
                h[1] = (_Float16)tanh_(v[1] + b4.y);
                h[2] = (_Float16)tanh_(v[2] + b4.z);
                h[3] = (_Float16)tanh_(v[3] + b4.w);
            } else {
                h[0] = (_Float16)sigmoid_(v[0] + b4.x);
                h[1] = (_Float16)sigmoid_(v[1] + b4.y);
                h[2] = (_Float16)sigmoid_(v[2] + b4.z);
                h[3] = (_Float16)sigmoid_(v[3] + b4.w);
            }
            *(f16x4*)(outp + gm * DDIM + gc) = h;
        }
    }
}

// ---------------------------------------------------------------------------
// Single-pass scan via ticket-ordered decoupled lookback (replaces pass1 +
// carry_scan + pass2).  512 blocks x 256 thr; each WARP owns one 16-step
// chunk (lane = d4 = 4 channels).  Ticket from atomicAdd assigns chunks in
// START order, so every dependency points to an already-resident block --
// deadlock-free regardless of dispatch order (G16-safe).
// Publish: local (A,B) -> release flag=1; after prefix resolution publish
// inclusive value -> release flag=2.  Lookback hops: accumulate flag=1
// aggregates, terminate on flag=2.  All flag ops AGENT scope (cross-XCD).
// z,f,o held in registers; out written directly.  ~89 MB total traffic.
// ---------------------------------------------------------------------------
__global__ __launch_bounds__(256) void scan_lookback(
    const _Float16* __restrict__ zbuf, const _Float16* __restrict__ fbuf,
    const _Float16* __restrict__ obuf, float* __restrict__ aggA,
    float* __restrict__ aggB, float* __restrict__ incB,
    int* __restrict__ flags, int* __restrict__ ticket,
    float* __restrict__ out) {
    __shared__ int vb_s;
    if (threadIdx.x == 0)
        vb_s = __hip_atomic_fetch_add(ticket, 1, __ATOMIC_RELAXED,
                                      __HIP_MEMORY_SCOPE_AGENT);
    __syncthreads();
    const int vb = vb_s;              // virtual block id, start-ordered
    const int b = vb & 7;             // b fastest: all 8 chains start early
    const int cg = vb >> 3;           // chunk group (4 chunks/block)
    const int d4 = threadIdx.x & 63;
    const int sub = threadIdx.x >> 6; // warp = one chunk
    const int chunk = cg * 4 + sub;
    const int idx = (b << 14) | (chunk << 6) | d4;

    const size_t row0 = (size_t)b * TDIM + (size_t)chunk * LCHUNK;
    const int2* zp = (const int2*)zbuf + row0 * 64 + d4;
    const int2* fp = (const int2*)fbuf + row0 * 64 + d4;
    const int2* op = (const int2*)obuf + row0 * 64 + d4;

    // Phase A: load chunk z,f into regs; compute local A=prod f, B=c_local.
    int2 zreg[LCHUNK], freg[LCHUNK], oreg[LCHUNK];
    float A[4], Bv[4];
#pragma unroll
    for (int e = 0; e < 4; ++e) { A[e] = 1.0f; Bv[e] = 0.0f; }
#pragma unroll
    for (int i = 0; i < LCHUNK; ++i) {
        freg[i] = fp[(size_t)i * 64];
        zreg[i] = zp[(size_t)i * 64];
        oreg[i] = op[(size_t)i * 64];  // prefetch o; consumed in replay
        const _Float16* fh = (const _Float16*)&freg[i];
        const _Float16* zh = (const _Float16*)&zreg[i];
#pragma unroll
        for (int e = 0; e < 4; ++e) {
            const float f = (float)fh[e];
            const float z = (float)zh[e];
            A[e] *= f;
            Bv[e] = f * Bv[e] + (1.0f - f) * z;
        }
    }

    // Publish local aggregate (chunk 0 goes straight to inclusive).
    if (chunk > 0) {
        ((float4*)aggA)[idx] = make_float4(A[0], A[1], A[2], A[3]);
        ((float4*)aggB)[idx] = make_float4(Bv[0], Bv[1], Bv[2], Bv[3]);
        __threadfence();
        __hip_atomic_store(&flags[idx], 1, __ATOMIC_RELEASE,
                           __HIP_MEMORY_SCOPE_AGENT);
    }

    // Lookback: resolve exclusive carry cin.
    float cin[4] = {0.f, 0.f, 0.f, 0.f};
    if (chunk > 0) {
        float Aacc[4] = {1.f, 1.f, 1.f, 1.f};
        float Bacc[4] = {0.f, 0.f, 0.f, 0.f};
        int j = chunk - 1;
        for (;;) {
            const int idxj = (b << 14) | (j << 6) | d4;
            int fl;
            do {
                fl = __hip_atomic_load(&flags[idxj], __ATOMIC_ACQUIRE,
                                       __HIP_MEMORY_SCOPE_AGENT);
            } while (fl == 0);
            if (fl == 2) {
                const float4 I = ((const float4*)incB)[idxj];
                cin[0] = Aacc[0] * I.x + Bacc[0];
                cin[1] = Aacc[1] * I.y + Bacc[1];
                cin[2] = Aacc[2] * I.z + Bacc[2];
                cin[3] = Aacc[3] * I.w + Bacc[3];
                break;
            }
            const float4 Aj = ((const float4*)aggA)[idxj];
            const float4 Bj = ((const float4*)aggB)[idxj];
            Bacc[0] = Aacc[0] * Bj.x + Bacc[0];
            Bacc[1] = Aacc[1] * Bj.y + Bacc[1];
            Bacc[2] = Aacc[2] * Bj.z + Bacc[2];
            Bacc[3] = Aacc[3] * Bj.w + Bacc[3];
            Aacc[0] *= Aj.x; Aacc[1] *= Aj.y;
            Aacc[2] *= Aj.z; Aacc[3] *= Aj.w;
            if (--j < 0) {  // unreachable (chunk 0 publishes inclusive)
                cin[0] = Bacc[0]; cin[1] = Bacc[1];
                cin[2] = Bacc[2]; cin[3] = Bacc[3];
                break;
            }
        }
    }

    // Publish inclusive value ASAP to unblock successors.
    if (chunk < NCHUNK - 1) {
        ((float4*)incB)[idx] =
            make_float4(A[0] * cin[0] + Bv[0], A[1] * cin[1] + Bv[1],
                        A[2] * cin[2] + Bv[2], A[3] * cin[3] + Bv[3]);
        __threadfence();
        __hip_atomic_store(&flags[idx], 2, __ATOMIC_RELEASE,
                           __HIP_MEMORY_SCOPE_AGENT);
    }

    // Replay with true carry; h = o*c.
    float c[4] = {cin[0], cin[1], cin[2], cin[3]};
    float4* hp = (float4*)out + row0 * 64 + d4;
#pragma unroll
    for (int i = 0; i < LCHUNK; ++i) {
        const _Float16* fh = (const _Float16*)&freg[i];
        const _Float16* zh = (const _Float16*)&zreg[i];
        const _Float16* oh = (const _Float16*)&oreg[i];
        float h[4];
#pragma unroll
        for (int e = 0; e < 4; ++e) {
            const float f = (float)fh[e];
            const float z = (float)zh[e];
            c[e] = f * c[e] + (1.0f - f) * z;
            h[e] = (float)oh[e] * c[e];
        }
        hp[(size_t)i * 64] = make_float4(h[0], h[1], h[2], h[3]);
    }
}

extern "C" void kernel_launch(void* const* d_in, const int* in_sizes, int n_in,
                              void* d_out, int out_size, void* d_ws,
                              size_t ws_size, hipStream_t stream) {
    const float* x = (const float*)d_in[0];
    const float* Wz = (const float*)d_in[1];
    const float* Wf = (const float*)d_in[2];
    const float* Wo = (const float*)d_in[3];
    const float* bz = (const float*)d_in[4];
    const float* bfv = (const float*)d_in[5];
    const float* bo = (const float*)d_in[6];
    float* out = (float*)d_out;

    // Workspace: xpad 16.78M | Wt 0.79M | z/f/o 3x16.78M | aggA 2M | aggB 2M
    // | incB 2M | flags 512K + ticket
    char* p = (char*)d_ws;
    _Float16* xpad = (_Float16*)p;  p += (size_t)BDIM * (TDIM + 1) * DDIM * 2;
    _Float16* Wt = (_Float16*)p;    p += (size_t)3 * 256 * 512 * 2;
    _Float16* zbuf = (_Float16*)p;  p += (size_t)MDIM * DDIM * 2;
    _Float16* fbuf = (_Float16*)p;  p += (size_t)MDIM * DDIM * 2;
    _Float16* obuf = (_Float16*)p;  p += (size_t)MDIM * DDIM * 2;
    float* aggA = (float*)p;        p += (size_t)BDIM * NCHUNK * DDIM * 4;
    float* aggB = (float*)p;        p += (size_t)BDIM * NCHUNK * DDIM * 4;
    float* incB = (float*)p;        p += (size_t)BDIM * NCHUNK * DDIM * 4;
    int* flags = (int*)p;           p += (size_t)BDIM * NCHUNK * 64 * 4;
    int* ticket = (int*)p;          p += 256;

    // Zero flags + ticket (graph-capturable stream op).
    hipMemsetAsync(flags, 0, (size_t)BDIM * NCHUNK * 64 * 4 + 256, stream);

    prep<<<1536 + 1025 * BDIM, 256, 0, stream>>>(x, xpad, Wz, Wf, Wo, Wt);

    gates_mfma<<<MDIM / 128 * (DDIM / 128) * 3, 256, 0, stream>>>(
        xpad, Wt, bz, bfv, bo, zbuf, fbuf, obuf);

    scan_lookback<<<512, 256, 0, stream>>>(zbuf, fbuf, obuf, aggA, aggB,
                                           incB, flags, ticket, out);
}

// Round 9
// 160.170 us; speedup vs baseline: 4.2599x; 4.2599x over previous
//
#include <hip/hip_runtime.h>
#include <hip/hip_bf16.h>
#include <hip/hip_fp16.h>

// Problem constants (B=8, T=4096, Din=Dout=256, WINDOW=2)
#define BDIM 8
#define TDIM 4096
#define DDIM 256
#define MDIM (BDIM * TDIM)      // 32768
#define NCHUNK 256              // chunks along T for the parallel scan
#define LCHUNK (TDIM / NCHUNK)  // 16

typedef _Float16 f16x8 __attribute__((ext_vector_type(8)));
typedef _Float16 f16x4 __attribute__((ext_vector_type(4)));
typedef float f32x4 __attribute__((ext_vector_type(4)));

__device__ __forceinline__ float sigmoid_(float x) {
    return 1.0f / (1.0f + __expf(-x));
}
__device__ __forceinline__ float tanh_(float x) {
    return 2.0f / (1.0f + __expf(-2.0f * x)) - 1.0f;
}

#define GLOAD_LDS16(g, l)                                                    \
    __builtin_amdgcn_global_load_lds(                                        \
        (const __attribute__((address_space(1))) void*)(g),                  \
        (__attribute__((address_space(3))) void*)(l), 16, 0, 0)

// ---------------------------------------------------------------------------
// Fused prep: blocks [0,1536) convert W, blocks [1536,9736) convert x.
// ---------------------------------------------------------------------------
__global__ __launch_bounds__(256) void prep(
    const float* __restrict__ x, _Float16* __restrict__ xpad,
    const float* __restrict__ Wz, const float* __restrict__ Wf,
    const float* __restrict__ Wo, _Float16* __restrict__ Wt) {
    const int bx = blockIdx.x;
    if (bx < 1536) {  // convert_w: 1536*256 = 3*2*256*256 threads
        const int idx = bx * 256 + threadIdx.x;
        const int n = idx & 255;
        const int kin = (idx >> 8) & 255;
        const int w = (idx >> 16) & 1;
        const int g = idx >> 17;
        const float* W = (g == 0) ? Wz : (g == 1) ? Wf : Wo;
        const float v = W[(size_t)w * 65536 + (size_t)kin * 256 + n];
        Wt[((size_t)g * 256 + n) * 512 + w * 256 + kin] = (_Float16)v;
        return;
    }
    const int bxx = bx - 1536;        // 8200 blocks: 1025 per batch
    const int b = bxx / 1025;
    const int tb = bxx - b * 1025;
    const int tp = tb * 4 + (threadIdx.x >> 6);  // padded row 0..4096
    const int q = threadIdx.x & 63;
    if (tp > TDIM) return;
    float4 v = make_float4(0.f, 0.f, 0.f, 0.f);
    if (tp > 0)
        v = *(const float4*)(x + ((size_t)b * TDIM + tp - 1) * DDIM + q * 4);
    f16x4 h;
    h[0] = (_Float16)v.x; h[1] = (_Float16)v.y;
    h[2] = (_Float16)v.z; h[3] = (_Float16)v.w;
    *(f16x4*)(xpad + ((size_t)b * (TDIM + 1) + tp) * DDIM + q * 4) = h;
}

// ---------------------------------------------------------------------------
// MFMA GEMM, counted-vmcnt 3-slot pipeline (R8 post-mortem: per-iteration
// vmcnt(0) full drain = ~3600 stall cyc/iter; counted waits need depth).
// BM=128 x BN=256 (full Dout), BK=64, 8 waves (512 thr), wave grid 2m x 4n
// (per-wave 64x64 out).  3 LDS slots of 48 KB (A 16K | B 32K) = 144 KB ->
// 1 block/CU, 2 waves/SIMD (same TLP as R7's 2x4-wave blocks).
// Ring: stage(t+2) issued at iter t; wait vmcnt(6) at iter top (stage(t)
// done, stage(t+1)'s 6 loads stay IN FLIGHT across the barrier) -- never
// drain to 0 mid-loop; each stage has ~2 iterations of cover.
// Slot safety: (t+2)%3 != t%3, != (t+1)%3; its readers (iter t-1) drained
// their ds_reads (lgkmcnt(0) before kk1 MFMAs) before iter-t barrier.
// Inner body (kk0/kk1 counted-lgkm split, XOR chunk swizzle with
// row&7==lane&7 invariant, swapped-operand epilogue) = R7-verified algebra.
// Grid 768 = 256 m-blocks x 3 gates = 3 even CU rounds; XCD swizzle
// bijective (768%8==0); gate innermost -> 3 sharers of each A-tile
// consecutive on one XCD.
// ---------------------------------------------------------------------------
__global__ __launch_bounds__(512, 2) void gates_mfma(
    const _Float16* __restrict__ xpad, const _Float16* __restrict__ Wt,
    const float* __restrict__ bz, const float* __restrict__ bfv,
    const float* __restrict__ bo,
    _Float16* __restrict__ zbuf, _Float16* __restrict__ fbuf,
    _Float16* __restrict__ obuf) {
    const int hw = blockIdx.x;                 // 768 blocks = 8 XCDs x 96
    const int logical = (hw & 7) * 96 + (hw >> 3);
    const int mblk = logical / 3;
    const int gate = logical - mblk * 3;       // gate innermost
    const int m0 = mblk * 128;

    const int tid = threadIdx.x;               // 0..511
    const int lane = tid & 63;
    const int wave = tid >> 6;                 // 0..7
    const int wm = wave >> 2;                  // 0..1 (m half)
    const int wn = wave & 3;                   // 0..3 (n quarter)

    // 3 slots x 48 KiB: A [128][64]h at +0, B [256][64]h at +16384.
    __shared__ __align__(16) char smem[147456];

    // Staging: thread covers row r1 = tid>>3 (+64 or +64*r per round),
    // chunk pos tid&7; linear dest (row,cpos) holds global chunk
    // cpos ^ (row&7); row&7 == (tid>>3)&7 for every round (steps of 64).
    const int r1 = tid >> 3;                             // 0..63
    const int kc = (((tid & 7) ^ ((tid >> 3) & 7))) * 8; // halves

    const int b = m0 >> 12;
    const int t0 = m0 & (TDIM - 1);

    const _Float16* srcA =
        xpad + ((size_t)b * (TDIM + 1) + t0 + r1) * DDIM + kc;
    const _Float16* srcB = Wt + ((size_t)gate * 256 + r1) * 512 + kc;

    // 6 loads/thread/K-tile: A rows {r1, r1+64}, B rows {r1,+64,+128,+192}.
#define STAGE_(slot, kt)                                                     \
    {                                                                        \
        char* dA = smem + (slot) * 49152 + tid * 16;                         \
        char* dB = smem + (slot) * 49152 + 16384 + tid * 16;                 \
        GLOAD_LDS16(srcA + (kt) * 64, dA);                                   \
        GLOAD_LDS16(srcA + (kt) * 64 + 64 * DDIM, dA + 8192);                \
        GLOAD_LDS16(srcB + (kt) * 64, dB);                                   \
        GLOAD_LDS16(srcB + (kt) * 64 + 64 * 512, dB + 8192);                 \
        GLOAD_LDS16(srcB + (kt) * 64 + 128 * 512, dB + 16384);               \
        GLOAD_LDS16(srcB + (kt) * 64 + 192 * 512, dB + 24576);               \
    }

    f32x4 acc[4][4] = {};
    const int am = lane & 15;
    // Read-side chunk for kk=0/1: chunk = (kk*4 + lane>>4) ^ (lane&7);
    // row&7 == lane&7 for every frag row (rows = mult16 + am).
    const int c0 = (((lane >> 4) ^ (lane & 7))) * 8;
    const int c1 = (((4 + (lane >> 4)) ^ (lane & 7))) * 8;

    // Prologue: stage K-tiles 0,1 into slots 0,1 (12 loads in flight).
    STAGE_(0, 0);
    STAGE_(1, 1);

#pragma unroll
    for (int t = 0; t < 8; ++t) {
        // Counted wait: stage(t) done, stage(t+1)'s 6 stay in flight.
        if (t < 7)
            asm volatile("s_waitcnt vmcnt(6)" ::: "memory");
        else
            asm volatile("s_waitcnt vmcnt(0)" ::: "memory");
        __builtin_amdgcn_s_barrier();
        __builtin_amdgcn_sched_barrier(0);
        if (t < 6) STAGE_((t + 2) % 3, t + 2);

        const _Float16* Ab = (const _Float16*)(smem + (t % 3) * 49152);
        const _Float16* Bb =
            (const _Float16*)(smem + (t % 3) * 49152 + 16384);

        f16x8 a0[4], b0[4], a1[4], b1[4];
#pragma unroll
        for (int i = 0; i < 4; ++i)
            a0[i] = *(const f16x8*)(Ab + (wm * 64 + i * 16 + am) * 64 + c0);
#pragma unroll
        for (int j = 0; j < 4; ++j)
            b0[j] = *(const f16x8*)(Bb + (wn * 64 + j * 16 + am) * 64 + c0);
        __builtin_amdgcn_sched_barrier(0);  // kk0 reads issue before kk1
#pragma unroll
        for (int i = 0; i < 4; ++i)
            a1[i] = *(const f16x8*)(Ab + (wm * 64 + i * 16 + am) * 64 + c1);
#pragma unroll
        for (int j = 0; j < 4; ++j)
            b1[j] = *(const f16x8*)(Bb + (wn * 64 + j * 16 + am) * 64 + c1);

        // kk0's 8 reads done; kk1's 8 stay in flight under the MFMAs.
        asm volatile("s_waitcnt lgkmcnt(8)" ::: "memory");
        __builtin_amdgcn_sched_barrier(0);  // rule 18: no MFMA hoist
        __builtin_amdgcn_s_setprio(1);
        // SWAPPED operands: per lane, acc[i][j] reg r = C[m][n] with
        // m = i*16 + (lane&15), n = j*16 + (lane>>4)*4 + r.
#pragma unroll
        for (int i = 0; i < 4; ++i)
#pragma unroll
            for (int j = 0; j < 4; ++j)
                acc[i][j] = __builtin_amdgcn_mfma_f32_16x16x32_f16(
                    b0[j], a0[i], acc[i][j], 0, 0, 0);
        __builtin_amdgcn_s_setprio(0);
        asm volatile("s_waitcnt lgkmcnt(0)" ::: "memory");
        __builtin_amdgcn_sched_barrier(0);
        __builtin_amdgcn_s_setprio(1);
#pragma unroll
        for (int i = 0; i < 4; ++i)
#pragma unroll
            for (int j = 0; j < 4; ++j)
                acc[i][j] = __builtin_amdgcn_mfma_f32_16x16x32_f16(
                    b1[j], a1[i], acc[i][j], 0, 0, 0);
        __builtin_amdgcn_s_setprio(0);
    }
#undef STAGE_

    // Epilogue: per (i,j) frag = 4 consecutive columns at one row.
    // float4 bias load, activation, one 8-B f16x4 store. No LDS, no barrier.
    const float* bias = (gate == 0) ? bz : (gate == 1) ? bfv : bo;
    _Float16* outp = (gate == 0) ? zbuf : (gate == 1) ? fbuf : obuf;
    const int nq = (lane >> 4) * 4;
#pragma unroll
    for (int i = 0; i < 4; ++i) {
        const size_t gm = (size_t)(m0 + wm * 64 + i * 16 + am);
#pragma unroll
        for (int j = 0; j < 4; ++j) {
            const int gc = wn * 64 + j * 16 + nq;
            const float4 b4 = *(const float4*)(bias + gc);
            f32x4 v = acc[i][j];
            f16x4 h;
            if (gate == 0) {
                h[0] = (_Float16)tanh_(v[0] + b4.x);
                h[1] = (_Float16)tanh_(v[1] + b4.y);
                h[2] = (_Float16)tanh_(v[2] + b4.z);
                h[3] = (_Float16)tanh_(v[3] + b4.w);
            } else {
                h[0] = (_Float16)sigmoid_(v[0] + b4.x);
                h[1] = (_Float16)sigmoid_(v[1] + b4.y);
                h[2] = (_Float16)sigmoid_(v[2] + b4.z);
                h[3] = (_Float16)sigmoid_(v[3] + b4.w);
            }
            *(f16x4*)(outp + gm * DDIM + gc) = h;
        }
    }
}

// ---------------------------------------------------------------------------
// Scan pass 1: per-chunk aggregates over LCHUNK steps from c=0; A = prod(f).
// 4 channels/thread -> 131072 threads (2 waves/SIMD) for latency hiding.
// ---------------------------------------------------------------------------
__global__ __launch_bounds__(256) void scan_pass1(
    const _Float16* __restrict__ zbuf, const _Float16* __restrict__ fbuf,
    float* __restrict__ aggA, float* __restrict__ aggB) {
    const int idx = blockIdx.x * 256 + threadIdx.x;  // < B*NCHUNK*64 = 131072
    const int d4 = idx & 63;
    const int chunk = (idx >> 6) & (NCHUNK - 1);
    const int b = idx >> 14;

    const size_t row0 = (size_t)b * TDIM + (size_t)chunk * LCHUNK;
    const int2* zp = (const int2*)zbuf + row0 * 64 + d4;
    const int2* fp = (const int2*)fbuf + row0 * 64 + d4;

    float A[4], c[4];
#pragma unroll
    for (int e = 0; e < 4; ++e) { A[e] = 1.0f; c[e] = 0.0f; }

    for (int i = 0; i < LCHUNK; ++i) {
        int2 fv = *fp;
        int2 zv = *zp;
        const _Float16* fh = (const _Float16*)&fv;
        const _Float16* zh = (const _Float16*)&zv;
#pragma unroll
        for (int e = 0; e < 4; ++e) {
            const float f = (float)fh[e];
            const float z = (float)zh[e];
            A[e] *= f;
            c[e] = f * c[e] + (1.0f - f) * z;
        }
        fp += 64;
        zp += 64;
    }
    ((float4*)aggA)[idx] = make_float4(A[0], A[1], A[2], A[3]);
    ((float4*)aggB)[idx] = make_float4(c[0], c[1], c[2], c[3]);
}

// ---------------------------------------------------------------------------
// Carry scan across chunks: one thread per (b,d) = 2048 threads.
// Unroll-16 batched loads: 16 latency rounds instead of 32.
// ---------------------------------------------------------------------------
__global__ __launch_bounds__(256) void carry_scan(
    const float* __restrict__ aggA, const float* __restrict__ aggB,
    float* __restrict__ carry) {
    const int g = blockIdx.x * 256 + threadIdx.x;  // < B*D = 2048
    const int d = g & 255;
    const int b = g >> 8;
    const size_t base = (size_t)b * NCHUNK * 256 + d;

    float c = 0.0f;
    for (int ch0 = 0; ch0 < NCHUNK; ch0 += 16) {
        float A[16], Bv[16];
#pragma unroll
        for (int u = 0; u < 16; ++u) {
            const size_t p = base + (size_t)(ch0 + u) * 256;
            A[u] = aggA[p];
            Bv[u] = aggB[p];
        }
#pragma unroll
        for (int u = 0; u < 16; ++u) {
            const size_t p = base + (size_t)(ch0 + u) * 256;
            carry[p] = c;
            c = A[u] * c + Bv[u];
        }
    }
}

// ---------------------------------------------------------------------------
// Scan pass 2: replay chunk with true carry; h = o*c -> fp32 out.
// 4 channels/thread -> 131072 threads; one float4 store per step.
// ---------------------------------------------------------------------------
__global__ __launch_bounds__(256) void scan_pass2(
    const _Float16* __restrict__ zbuf, const _Float16* __restrict__ fbuf,
    const _Float16* __restrict__ obuf, const float* __restrict__ carry,
    float* __restrict__ out) {
    const int idx = blockIdx.x * 256 + threadIdx.x;  // < 131072
    const int d4 = idx & 63;
    const int chunk = (idx >> 6) & (NCHUNK - 1);
    const int b = idx >> 14;

    float c[4];
    const float4 c0 = ((const float4*)carry)[idx];
    c[0] = c0.x; c[1] = c0.y; c[2] = c0.z; c[3] = c0.w;

    const size_t row0 = (size_t)b * TDIM + (size_t)chunk * LCHUNK;
    const int2* zp = (const int2*)zbuf + row0 * 64 + d4;
    const int2* fp = (const int2*)fbuf + row0 * 64 + d4;
    const int2* op = (const int2*)obuf + row0 * 64 + d4;
    float4* hp = (float4*)out + row0 * 64 + d4;

    for (int i = 0; i < LCHUNK; ++i) {
        int2 fv = *fp;
        int2 zv = *zp;
        int2 ov = *op;
        const _Float16* fh = (const _Float16*)&fv;
        const _Float16* zh = (const _Float16*)&zv;
        const _Float16* oh = (const _Float16*)&ov;
        float h[4];
#pragma unroll
        for (int e = 0; e < 4; ++e) {
            const float f = (float)fh[e];
            const float z = (float)zh[e];
            c[e] = f * c[e] + (1.0f - f) * z;
            h[e] = (float)oh[e] * c[e];
        }
        *hp = make_float4(h[0], h[1], h[2], h[3]);
        fp += 64;
        zp += 64;
        op += 64;
        hp += 64;
    }
}

extern "C" void kernel_launch(void* const* d_in, const int* in_sizes, int n_in,
                              void* d_out, int out_size, void* d_ws,
                              size_t ws_size, hipStream_t stream) {
    const float* x = (const float*)d_in[0];
    const float* Wz = (const float*)d_in[1];
    const float* Wf = (const float*)d_in[2];
    const float* Wo = (const float*)d_in[3];
    const float* bz = (const float*)d_in[4];
    const float* bfv = (const float*)d_in[5];
    const float* bo = (const float*)d_in[6];
    float* out = (float*)d_out;

    // Workspace (bytes): xpad 16.78M | Wt 0.79M | z 16.78M | f 16.78M |
    // o 16.78M | aggA 2M | aggB 2M | carry 2M   -> ~74.7 MB
    char* p = (char*)d_ws;
    _Float16* xpad = (_Float16*)p;  p += (size_t)BDIM * (TDIM + 1) * DDIM * 2;
    _Float16* Wt = (_Float16*)p;    p += (size_t)3 * 256 * 512 * 2;
    _Float16* zbuf = (_Float16*)p;  p += (size_t)MDIM * DDIM * 2;
    _Float16* fbuf = (_Float16*)p;  p += (size_t)MDIM * DDIM * 2;
    _Float16* obuf = (_Float16*)p;  p += (size_t)MDIM * DDIM * 2;
    float* aggA = (float*)p;        p += (size_t)BDIM * NCHUNK * DDIM * 4;
    float* aggB = (float*)p;        p += (size_t)BDIM * NCHUNK * DDIM * 4;
    float* carry = (float*)p;

    prep<<<1536 + 1025 * BDIM, 256, 0, stream>>>(x, xpad, Wz, Wf, Wo, Wt);

    gates_mfma<<<768, 512, 0, stream>>>(xpad, Wt, bz, bfv, bo,
                                        zbuf, fbuf, obuf);

    scan_pass1<<<(BDIM * NCHUNK * 64) / 256, 256, 0, stream>>>(zbuf, fbuf,
                                                               aggA, aggB);
    carry_scan<<<(BDIM * DDIM) / 256, 256, 0, stream>>>(aggA, aggB, carry);
    scan_pass2<<<(BDIM * NCHUNK * 64) / 256, 256, 0, stream>>>(zbuf, fbuf,
                                                               obuf, carry, out);
}